// Round 8
// baseline (370.988 us; speedup 1.0000x reference)
//
#include <hip/hip_runtime.h>
#include <math.h>

// ===========================================================================
// CoAtten2: C=1024, H=W=64, HW=4096. Split-bf16 MFMA pipeline (3-term:
// ah*bh + ah*bl + al*bh, fp32 acc ~= 2^-15 rel precision at matrix-core rate).
//
// R8 changes vs R7 (measured: MfmaUtil 27% == clean single-buffer LDS-pipe
// ceiling; conflicts 0):
//   - A-operand DIRECT from global (per-lane contiguous 16B dwordx4; weights
//     L1/L2-hot) -> As_* removed from LDS; LDS frag reads halved.
//   - B double-buffered (2 x 16KB, same 32KB block total), ONE barrier/iter;
//     order sync -> A-loads -> next-B-DMA -> ds_read -> MFMA so the barrier
//     vmcnt(0) drain only waits DMA issued a full compute phase ago, and
//     MFMA's waitcnt (vmcnt(4)) retires A-loads without draining the DMA.
//   - final GEMM 2-term (drop Am_l*V_h; probs in [0,1] -> +<=~0.004 abs err).
//     Convs + logits stay 3-term.
// ===========================================================================

typedef __attribute__((ext_vector_type(8))) short    bf16x8;   // MFMA A/B frag
typedef __attribute__((ext_vector_type(4))) float    f32x4;    // MFMA C/D frag

__device__ __forceinline__ unsigned short f2bf(float x) {
    unsigned u = __float_as_uint(x);
    u += 0x7FFFu + ((u >> 16) & 1u);    // round-to-nearest-even
    return (unsigned short)(u >> 16);
}
__device__ __forceinline__ float bf2f(unsigned short h) {
    return __uint_as_float(((unsigned)h) << 16);
}
__device__ __forceinline__ void split2(float x, unsigned short& h, unsigned short& l) {
    h = f2bf(x);
    l = f2bf(x - bf2f(h));
}

// Async global->LDS DMA, 16B per lane. LDS dest = wave-uniform base + lane*16.
__device__ __forceinline__ void gld16(const unsigned short* g, unsigned short* l) {
    __builtin_amdgcn_global_load_lds(
        (const __attribute__((address_space(1))) unsigned int*)g,
        (__attribute__((address_space(3))) unsigned int*)l,
        16, 0, 0);
}

// ---------------------------------------------------------------------------
// All-weights split: flat over [Wq|Wk1|Wk2|Wv]. Grid 2560 x 1024 elems.
__global__ __launch_bounds__(256) void weights_split_k(
    const float* __restrict__ Wq, const float* __restrict__ Wk1,
    const float* __restrict__ Wk2, const float* __restrict__ Wv,
    unsigned short* __restrict__ Wqh, unsigned short* __restrict__ Wql,
    unsigned short* __restrict__ Wk1h, unsigned short* __restrict__ Wk1l,
    unsigned short* __restrict__ Wk2h, unsigned short* __restrict__ Wk2l,
    unsigned short* __restrict__ Wvh, unsigned short* __restrict__ Wvl)
{
    const int gi = blockIdx.x;
    const float* src; unsigned short *H, *L; int base;
    if (gi < 512)       { src = Wq;  H = Wqh;  L = Wql;  base = gi; }
    else if (gi < 1024) { src = Wk1; H = Wk1h; L = Wk1l; base = gi - 512; }
    else if (gi < 1536) { src = Wk2; H = Wk2h; L = Wk2l; base = gi - 1024; }
    else                { src = Wv;  H = Wvh;  L = Wvl;  base = gi - 1536; }
    const size_t i = (size_t)base * 1024 + threadIdx.x * 4;
    const float4 v = *(const float4*)(src + i);
    ushort4 h, l;
    split2(v.x, h.x, l.x); split2(v.y, h.y, l.y);
    split2(v.z, h.z, l.z); split2(v.w, h.w, l.w);
    *(ushort4*)(H + i) = h;
    *(ushort4*)(L + i) = l;
}

// ---------------------------------------------------------------------------
// Transpose + split for the 3 inputs in one launch (z selects which).
__global__ __launch_bounds__(256) void transpose3_k(
    const float* __restrict__ x0, const float* __restrict__ x1,
    const float* __restrict__ x2,
    unsigned short* __restrict__ t0h, unsigned short* __restrict__ t0l,
    unsigned short* __restrict__ t1h, unsigned short* __restrict__ t1l,
    unsigned short* __restrict__ t2h, unsigned short* __restrict__ t2l)
{
    const float* X; unsigned short *Th, *Tl;
    if (blockIdx.z == 0)      { X = x0; Th = t0h; Tl = t0l; }
    else if (blockIdx.z == 1) { X = x1; Th = t1h; Tl = t1l; }
    else                      { X = x2; Th = t2h; Tl = t2l; }

    __shared__ float t[32 * 33];
    const int tid = threadIdx.x;
    const int c0 = blockIdx.y * 32;
    const int p0 = blockIdx.x * 32;

    const int cl = tid >> 3;
    const int p4 = (tid & 7) * 4;
    const float4 v = *(const float4*)(X + (size_t)(c0 + cl) * 4096 + p0 + p4);
    t[(p4 + 0) * 33 + cl] = v.x;
    t[(p4 + 1) * 33 + cl] = v.y;
    t[(p4 + 2) * 33 + cl] = v.z;
    t[(p4 + 3) * 33 + cl] = v.w;
    __syncthreads();

    const int pl = tid >> 3;
    const int c4 = (tid & 7) * 4;
    ushort4 h, l;
    split2(t[pl * 33 + c4 + 0], h.x, l.x);
    split2(t[pl * 33 + c4 + 1], h.y, l.y);
    split2(t[pl * 33 + c4 + 2], h.z, l.z);
    split2(t[pl * 33 + c4 + 3], h.w, l.w);
    const size_t o = (size_t)(p0 + pl) * 1024 + c0 + c4;
    *(ushort4*)(Th + o) = h;
    *(ushort4*)(Tl + o) = l;
}

// Single-matrix transpose+split (for V; bias already applied in conv epilogue).
__global__ __launch_bounds__(256) void transpose1_k(
    const float* __restrict__ X,
    unsigned short* __restrict__ Th, unsigned short* __restrict__ Tl)
{
    __shared__ float t[32 * 33];
    const int tid = threadIdx.x;
    const int c0 = blockIdx.y * 32;
    const int p0 = blockIdx.x * 32;

    const int cl = tid >> 3;
    const int p4 = (tid & 7) * 4;
    const float4 v = *(const float4*)(X + (size_t)(c0 + cl) * 4096 + p0 + p4);
    t[(p4 + 0) * 33 + cl] = v.x;
    t[(p4 + 1) * 33 + cl] = v.y;
    t[(p4 + 2) * 33 + cl] = v.z;
    t[(p4 + 3) * 33 + cl] = v.w;
    __syncthreads();

    const int pl = tid >> 3;
    const int c4 = (tid & 7) * 4;
    ushort4 h, l;
    split2(t[pl * 33 + c4 + 0], h.x, l.x);
    split2(t[pl * 33 + c4 + 1], h.y, l.y);
    split2(t[pl * 33 + c4 + 2], h.z, l.z);
    split2(t[pl * 33 + c4 + 3], h.w, l.w);
    const size_t o = (size_t)(p0 + pl) * 1024 + c0 + c4;
    *(ushort4*)(Th + o) = h;
    *(ushort4*)(Tl + o) = l;
}

// ---------------------------------------------------------------------------
// GEMM core v3: A direct-from-global, B DMA-staged double-buffered.
// acc += A[m0+..][kbeg..kend) (x) B[n0+..][..), NT, row stride ldk.
// 128x128 tile, BK=32, 4 waves 2x2, wave 64x64 = 4x4 MFMA(16x16x32) tiles.
// TERMS=3: ah*bh + ah*bl + al*bh.  TERMS=2: ah*bh + ah*bl (A low part unused).
// B LDS layout (swizzled, conflict-free): row*32 + ((seg+(row>>1))&3)*8.
// Frag layouts (HW-verified m89/m91): A/B [row=lane&15][k=quad*8+j],
// C/D [row=quad*4+reg][col=lane&15].
template<int TERMS>
__device__ __forceinline__ void gemm_core(
    const unsigned short* __restrict__ Ah, const unsigned short* __restrict__ Al,
    const unsigned short* __restrict__ Bh, const unsigned short* __restrict__ Bl,
    int ldk, int kbeg, int kend, int m0, int n0,
    unsigned short* Bs_h, unsigned short* Bs_l,   // each [2][128*32]
    f32x4 (&acc)[4][4])
{
    const int tid  = threadIdx.x;
    const int lane = tid & 63;
    const int wv   = tid >> 6;
    const int wm   = (wv >> 1) * 64;
    const int wn   = (wv & 1) * 64;
    const int lr   = lane & 15;
    const int quad = lane >> 4;

    // --- B staging: waves {0,1} -> Bs_h, waves {2,3} -> Bs_l; 4 insts/wave ---
    const unsigned short* gsrc = (wv < 2) ? Bh : Bl;
    unsigned short* ldst = (wv < 2) ? Bs_h : Bs_l;
    const int tt0  = (wv & 1) * 4;                          // inst slots 0..3 / 4..7
    const int lrow = lane >> 2;                             // 0..15 rows in group
    const int gseg = ((lane & 3) - ((lane >> 3) & 3)) & 3;  // store-side swizzle
    const unsigned short* gp[4];
#pragma unroll
    for (int u = 0; u < 4; ++u)
        gp[u] = gsrc + (size_t)(n0 + (tt0 + u) * 16 + lrow) * ldk + kbeg + gseg * 8;

    // --- A direct frag pointers (per-lane contiguous 16B) ---
    const unsigned short* ap[4];
    const unsigned short* apl[4];
#pragma unroll
    for (int i = 0; i < 4; ++i) {
        const size_t ro = (size_t)(m0 + wm + i * 16 + lr) * ldk + kbeg + quad * 8;
        ap[i] = Ah + ro;
        apl[i] = (TERMS == 3) ? (Al + ro) : nullptr;
    }

    const int rdseg = (quad + (lr >> 1)) & 3;               // read-side swizzle

    // prologue: DMA first B slab into buf 0
#pragma unroll
    for (int u = 0; u < 4; ++u) {
        gld16(gp[u], ldst + (tt0 + u) * 512);
        gp[u] += 32;
    }

    int buf = 0;
    for (int k0 = kbeg; k0 < kend; k0 += 32) {
        __syncthreads();    // drains DMA issued last iter (full compute phase old)

        // A-frags for this iter -- issued BEFORE next DMA so MFMA's waitcnt
        // retires them at vmcnt(4) without draining the in-flight DMA.
        bf16x8 afh[4], afl[4];
#pragma unroll
        for (int i = 0; i < 4; ++i) {
            afh[i] = *(const bf16x8*)ap[i];  ap[i] += 32;
            if (TERMS == 3) { afl[i] = *(const bf16x8*)apl[i]; apl[i] += 32; }
        }
        // next B slab -> other buffer
        if (k0 + 32 < kend) {
#pragma unroll
            for (int u = 0; u < 4; ++u) {
                gld16(gp[u], ldst + (buf ^ 1) * 4096 + (tt0 + u) * 512);
                gp[u] += 32;
            }
        }
        // B frags from current buffer
        bf16x8 bfh[4], bfl[4];
#pragma unroll
        for (int j = 0; j < 4; ++j) {
            const int rb = buf * 4096 + (wn + j * 16 + lr) * 32 + rdseg * 8;
            bfh[j] = *(const bf16x8*)(Bs_h + rb);
            bfl[j] = *(const bf16x8*)(Bs_l + rb);
        }
#pragma unroll
        for (int i = 0; i < 4; ++i)
#pragma unroll
            for (int j = 0; j < 4; ++j) {
                acc[i][j] = __builtin_amdgcn_mfma_f32_16x16x32_bf16(afh[i], bfh[j], acc[i][j], 0, 0, 0);
                acc[i][j] = __builtin_amdgcn_mfma_f32_16x16x32_bf16(afh[i], bfl[j], acc[i][j], 0, 0, 0);
                if (TERMS == 3)
                    acc[i][j] = __builtin_amdgcn_mfma_f32_16x16x32_bf16(afl[i], bfh[j], acc[i][j], 0, 0, 0);
            }
        buf ^= 1;
    }
}

#define GEMM_PROLOGUE()                                                 \
    __shared__ __align__(16) unsigned short Bs_h[2 * 128 * 32];         \
    __shared__ __align__(16) unsigned short Bs_l[2 * 128 * 32];         \
    f32x4 acc[4][4];                                                    \
    _Pragma("unroll") for (int i = 0; i < 4; ++i)                       \
    _Pragma("unroll") for (int j = 0; j < 4; ++j)                       \
    _Pragma("unroll") for (int r = 0; r < 4; ++r) acc[i][j][r] = 0.f;   \
    const int lane = threadIdx.x & 63;                                  \
    const int wv   = threadIdx.x >> 6;                                  \
    const int wm   = (wv >> 1) * 64;                                    \
    const int wn   = (wv & 1) * 64;                                     \
    const int lr   = lane & 15;                                         \
    const int quad = lane >> 4;                                         \
    (void)lane; (void)wv;

// ---------------------------------------------------------------------------
// ALL FOUR convs, one launch. m-tiles (blockIdx.y, 0..19) partition
// [Wq(4) | Wk1(4) | Wk2(4) | Wv(8)]. Grid (32,20) = 640 blocks. 3-term.
__global__ __launch_bounds__(256) void conv_all_k(
    const unsigned short* __restrict__ Wqh, const unsigned short* __restrict__ Wql,
    const unsigned short* __restrict__ Wk1h, const unsigned short* __restrict__ Wk1l,
    const unsigned short* __restrict__ Wk2h, const unsigned short* __restrict__ Wk2l,
    const unsigned short* __restrict__ Wvh, const unsigned short* __restrict__ Wvl,
    const unsigned short* __restrict__ xmTh, const unsigned short* __restrict__ xmTl,
    const unsigned short* __restrict__ xfTh, const unsigned short* __restrict__ xfTl,
    const unsigned short* __restrict__ xlTh, const unsigned short* __restrict__ xlTl,
    const float* __restrict__ bq, const float* __restrict__ bk1,
    const float* __restrict__ bk2, const float* __restrict__ bv,
    unsigned short* __restrict__ Qh, unsigned short* __restrict__ Ql,
    unsigned short* __restrict__ Kfh, unsigned short* __restrict__ Kfl,
    unsigned short* __restrict__ Klh, unsigned short* __restrict__ Kll,
    float* __restrict__ V)
{
    GEMM_PROLOGUE();
    const int mt = blockIdx.y;
    const unsigned short *Ah, *Al, *Bh, *Bl;
    const float* bias;
    unsigned short *Ch = nullptr, *Cl = nullptr;
    float* Cv = nullptr;
    int mloc;
    if (mt < 4) {
        Ah = Wqh;  Al = Wql;  Bh = xmTh; Bl = xmTl; bias = bq;
        Ch = Qh;   Cl = Ql;   mloc = mt * 128;
    } else if (mt < 8) {
        Ah = Wk1h; Al = Wk1l; Bh = xfTh; Bl = xfTl; bias = bk1;
        Ch = Kfh;  Cl = Kfl;  mloc = (mt - 4) * 128;
    } else if (mt < 12) {
        Ah = Wk2h; Al = Wk2l; Bh = xlTh; Bl = xlTl; bias = bk2;
        Ch = Klh;  Cl = Kll;  mloc = (mt - 8) * 128;
    } else {
        Ah = Wvh;  Al = Wvl;  Bh = xmTh; Bl = xmTl; bias = bv;
        Cv = V;    mloc = (mt - 12) * 128;
    }
    const int n0 = blockIdx.x * 128;

    gemm_core<3>(Ah, Al, Bh, Bl, 1024, 0, 1024, mloc, n0, Bs_h, Bs_l, acc);

#pragma unroll
    for (int i = 0; i < 4; ++i) {
        const int mb = mloc + wm + i * 16 + quad * 4;
#pragma unroll
        for (int j = 0; j < 4; ++j) {
            const int nn = n0 + wn + j * 16 + lr;
#pragma unroll
            for (int r = 0; r < 4; ++r) {
                const float v = acc[i][j][r] + bias[mb + r];
                const size_t idx = (size_t)(mb + r) * 4096 + nn;
                if (Cv) {
                    Cv[idx] = v;
                } else {
                    unsigned short h, l;
                    split2(v, h, l);
                    Ch[idx] = h;
                    Cl[idx] = l;
                }
            }
        }
    }
}

// ---------------------------------------------------------------------------
// Fused logits, split-K: z = which(f/l)*4 + kslice(0..3), K=512 per block.
// S = K' (x) Q', M=N=1024, ldk=2048. Grid (8,8,8) = 512 blocks. 3-term.
__global__ __launch_bounds__(256) void logits_fused_k(
    const unsigned short* __restrict__ Kfh, const unsigned short* __restrict__ Kfl,
    const unsigned short* __restrict__ Klh, const unsigned short* __restrict__ Kll,
    const unsigned short* __restrict__ Qh, const unsigned short* __restrict__ Ql,
    float* __restrict__ Sfp, float* __restrict__ Slp)
{
    GEMM_PROLOGUE();
    const int which = blockIdx.z >> 2;
    const int slice = blockIdx.z & 3;
    const unsigned short* Ah = which ? Klh : Kfh;
    const unsigned short* Al = which ? Kll : Kfl;
    float* out = (which ? Slp : Sfp) + (size_t)slice * 1024 * 1024;
    const int m0 = blockIdx.y * 128;
    const int n0 = blockIdx.x * 128;

    gemm_core<3>(Ah, Al, Qh, Ql, 2048, slice * 512, slice * 512 + 512, m0, n0,
                 Bs_h, Bs_l, acc);

#pragma unroll
    for (int i = 0; i < 4; ++i) {
        const int mb = m0 + wm + i * 16 + quad * 4;
#pragma unroll
        for (int j = 0; j < 4; ++j) {
            const int nn = n0 + wn + j * 16 + lr;
#pragma unroll
            for (int r = 0; r < 4; ++r)
                out[(size_t)(mb + r) * 1024 + nn] = acc[i][j][r];
        }
    }
}

// ---------------------------------------------------------------------------
// Final: out = gamma*(A (x) VT) + 0.5*(xf+xl). M=1024, N=4096, K=1024.
// Grid (32,8) = 256 blocks. 2-term (A = attention probs; Am_l term dropped).
__global__ __launch_bounds__(256) void gemm_final_k(
    const unsigned short* __restrict__ Amh, const unsigned short* __restrict__ Aml,
    const unsigned short* __restrict__ VTh, const unsigned short* __restrict__ VTl,
    float* __restrict__ out,
    const float* __restrict__ xf, const float* __restrict__ xl,
    const float* __restrict__ gamma)
{
    GEMM_PROLOGUE();
    const int m0 = blockIdx.y * 128;
    const int n0 = blockIdx.x * 128;

    gemm_core<2>(Amh, Aml, VTh, VTl, 1024, 0, 1024, m0, n0, Bs_h, Bs_l, acc);

    const float g = gamma[0];
#pragma unroll
    for (int i = 0; i < 4; ++i) {
        const int mb = m0 + wm + i * 16 + quad * 4;
#pragma unroll
        for (int j = 0; j < 4; ++j) {
            const int nn = n0 + wn + j * 16 + lr;
#pragma unroll
            for (int r = 0; r < 4; ++r) {
                const size_t idx = (size_t)(mb + r) * 4096 + nn;
                out[idx] = g * acc[i][j][r] + 0.5f * (xf[idx] + xl[idx]);
            }
        }
    }
}

// ---------------------------------------------------------------------------
// Row softmax over 4-slice partial sums: A = sm(sum Sfp) + sm(sum Slp),
// split-bf16 output. One block per row.
__global__ __launch_bounds__(256) void softmax_add4_k(
    const float* __restrict__ Sfp, const float* __restrict__ Slp,
    unsigned short* __restrict__ Ah, unsigned short* __restrict__ Al)
{
    const int row = blockIdx.x;
    const int tid = threadIdx.x;
    __shared__ float red[8];
    const size_t base = (size_t)row * 1024 + tid * 4;
    const size_t SL = (size_t)1024 * 1024;

    float4 vf = *(const float4*)(Sfp + base);
    float4 vl = *(const float4*)(Slp + base);
#pragma unroll
    for (int s = 1; s < 4; ++s) {
        const float4 a = *(const float4*)(Sfp + s * SL + base);
        const float4 b = *(const float4*)(Slp + s * SL + base);
        vf.x += a.x; vf.y += a.y; vf.z += a.z; vf.w += a.w;
        vl.x += b.x; vl.y += b.y; vl.z += b.z; vl.w += b.w;
    }

    float mf = fmaxf(fmaxf(vf.x, vf.y), fmaxf(vf.z, vf.w));
    float ml = fmaxf(fmaxf(vl.x, vl.y), fmaxf(vl.z, vl.w));
#pragma unroll
    for (int off = 32; off; off >>= 1) {
        mf = fmaxf(mf, __shfl_down(mf, off, 64));
        ml = fmaxf(ml, __shfl_down(ml, off, 64));
    }
    const int wave = tid >> 6;
    if ((tid & 63) == 0) { red[wave] = mf; red[4 + wave] = ml; }
    __syncthreads();
    mf = fmaxf(fmaxf(red[0], red[1]), fmaxf(red[2], red[3]));
    ml = fmaxf(fmaxf(red[4], red[5]), fmaxf(red[6], red[7]));
    __syncthreads();

    const float4 ef = make_float4(expf(vf.x - mf), expf(vf.y - mf),
                                  expf(vf.z - mf), expf(vf.w - mf));
    const float4 el = make_float4(expf(vl.x - ml), expf(vl.y - ml),
                                  expf(vl.z - ml), expf(vl.w - ml));
    float sf = ef.x + ef.y + ef.z + ef.w;
    float sl = el.x + el.y + el.z + el.w;
#pragma unroll
    for (int off = 32; off; off >>= 1) {
        sf += __shfl_down(sf, off, 64);
        sl += __shfl_down(sl, off, 64);
    }
    if ((tid & 63) == 0) { red[wave] = sf; red[4 + wave] = sl; }
    __syncthreads();
    sf = red[0] + red[1] + red[2] + red[3];
    sl = red[4] + red[5] + red[6] + red[7];

    const float rf = 1.f / sf, rl = 1.f / sl;
    ushort4 h, l;
    split2(ef.x * rf + el.x * rl, h.x, l.x);
    split2(ef.y * rf + el.y * rl, h.y, l.y);
    split2(ef.z * rf + el.z * rl, h.z, l.z);
    split2(ef.w * rf + el.w * rl, h.w, l.w);
    *(ushort4*)(Ah + base) = h;
    *(ushort4*)(Al + base) = l;
}

__global__ void noop_k(float* p) { if (threadIdx.x == 1024) p[0] = 0.f; }

// ===========================================================================
extern "C" void kernel_launch(void* const* d_in, const int* in_sizes, int n_in,
                              void* d_out, int out_size, void* d_ws, size_t ws_size,
                              hipStream_t stream) {
    (void)in_sizes; (void)n_in; (void)out_size;
    const float* xf  = (const float*)d_in[0];
    const float* xm  = (const float*)d_in[1];
    const float* xl  = (const float*)d_in[2];
    const float* Wq  = (const float*)d_in[3];
    const float* bq  = (const float*)d_in[4];
    const float* Wk1 = (const float*)d_in[5];
    const float* bk1 = (const float*)d_in[6];
    const float* Wk2 = (const float*)d_in[7];
    const float* bk2 = (const float*)d_in[8];
    const float* Wv  = (const float*)d_in[9];
    const float* bv  = (const float*)d_in[10];
    const float* gamma = (const float*)d_in[11];
    float* out = (float*)d_out;

    const size_t MB = 1024 * 1024;
    if (ws_size < 98 * MB) {
        noop_k<<<dim3(1), dim3(64), 0, stream>>>((float*)d_ws);
        return;
    }

    // ---- workspace layout (byte offsets, 98 MB total) ----
    char* p = (char*)d_ws;
    unsigned short* xmT_h = (unsigned short*)(p + 0 * MB);    // [4096][1024] bf16
    unsigned short* xmT_l = (unsigned short*)(p + 8 * MB);
    unsigned short* xfT_h = (unsigned short*)(p + 16 * MB);
    unsigned short* xfT_l = (unsigned short*)(p + 24 * MB);
    unsigned short* xlT_h = (unsigned short*)(p + 32 * MB);
    unsigned short* xlT_l = (unsigned short*)(p + 40 * MB);
    unsigned short* Wq_h  = (unsigned short*)(p + 48 * MB);
    unsigned short* Wq_l  = (unsigned short*)(p + 49 * MB);
    unsigned short* Wk1_h = (unsigned short*)(p + 50 * MB);
    unsigned short* Wk1_l = (unsigned short*)(p + 51 * MB);
    unsigned short* Wk2_h = (unsigned short*)(p + 52 * MB);
    unsigned short* Wk2_l = (unsigned short*)(p + 53 * MB);
    unsigned short* Wv_h  = (unsigned short*)(p + 54 * MB);
    unsigned short* Wv_l  = (unsigned short*)(p + 56 * MB);
    unsigned short* Q_h   = (unsigned short*)(p + 58 * MB);   // [1024][2048] bf16 view
    unsigned short* Q_l   = (unsigned short*)(p + 62 * MB);
    unsigned short* Kf_h  = (unsigned short*)(p + 66 * MB);
    unsigned short* Kf_l  = (unsigned short*)(p + 70 * MB);
    unsigned short* Kl_h  = (unsigned short*)(p + 74 * MB);
    unsigned short* Kl_l  = (unsigned short*)(p + 78 * MB);
    float*          V     = (float*)(p + 82 * MB);            // [1024][4096] f32 (+bias)
    // lifetime-based reuse (launch order: convs -> logits -> V transpose ->
    // softmax -> final):
    float*          Sfp  = (float*)(p + 16 * MB);  // [4][1024][1024] over xfT (dead after convs)
    float*          Slp  = (float*)(p + 32 * MB);  // over xlT
    unsigned short* VT_h = xmT_h;                  // over xmT (dead after convs)
    unsigned short* VT_l = xmT_l;
    unsigned short* Am_h = (unsigned short*)(p + 74 * MB);  // over Kl (dead after logits)
    unsigned short* Am_l = (unsigned short*)(p + 76 * MB);

    const dim3 blk(256);
    // prep (2 launches): transpose+split the 3 inputs; split the 4 weights
    transpose3_k<<<dim3(128, 32, 3), blk, 0, stream>>>(
        xm, xf, xl, xmT_h, xmT_l, xfT_h, xfT_l, xlT_h, xlT_l);
    weights_split_k<<<dim3(2560), blk, 0, stream>>>(
        Wq, Wk1, Wk2, Wv, Wq_h, Wq_l, Wk1_h, Wk1_l, Wk2_h, Wk2_l, Wv_h, Wv_l);
    // ALL convs, one launch (640 blocks)
    conv_all_k<<<dim3(32, 20), blk, 0, stream>>>(
        Wq_h, Wq_l, Wk1_h, Wk1_l, Wk2_h, Wk2_l, Wv_h, Wv_l,
        xmT_h, xmT_l, xfT_h, xfT_l, xlT_h, xlT_l,
        bq, bk1, bk2, bv,
        Q_h, Q_l, Kf_h, Kf_l, Kl_h, Kl_l, V);
    // logits fused + split-K=4 (512 blocks) -> partials over xfT/xlT regions
    logits_fused_k<<<dim3(8, 8, 8), blk, 0, stream>>>(
        Kf_h, Kf_l, Kl_h, Kl_l, Q_h, Q_l, Sfp, Slp);
    // VT = transpose+split(V) over dead xmT region
    transpose1_k<<<dim3(128, 32), blk, 0, stream>>>(V, VT_h, VT_l);
    // A = softmax(sum Sfp) + softmax(sum Slp), split output over dead Kl region
    softmax_add4_k<<<dim3(1024), blk, 0, stream>>>(Sfp, Slp, Am_h, Am_l);
    // out = gamma*(A (x) VT) + (xf+xl)/2   (256 blocks)
    gemm_final_k<<<dim3(32, 8), blk, 0, stream>>>(
        Am_h, Am_l, VT_h, VT_l, out, xf, xl, gamma);
}

// Round 9
// 302.310 us; speedup vs baseline: 1.2272x; 1.2272x over previous
//
#include <hip/hip_runtime.h>
#include <math.h>

// ===========================================================================
// CoAtten2: C=1024, H=W=64, HW=4096. Split-bf16 MFMA pipeline (3-term:
// ah*bh + ah*bl + al*bh; final GEMM 2-term with A=probs, validated R8).
//
// R9 changes vs R8 (R8 regressed: A-direct loads were uncoalesced, 16 cache
// lines per instr -> latency-bound, MfmaUtil 17%):
//   - A operands stored PRE-SWIZZLED in MFMA-frag-major layout:
//     off(m,k) = ((m>>4)*(K/32) + (k>>5))*512 + ((k>>3)&3)*128 + (m&15)*8 + (k&7)
//     so a wave's A-frag global load = base + lane*16B, fully coalesced 1KB.
//     Producers updated: weights_split (conv A), conv epilogue (Kf/Kl =
//     logits A), softmax (Am = final A). Q/V/xT stay row-major (B operands).
//   - B keeps DMA->LDS (conflict-free swizzle), double-buffered, 1 barrier.
//   - LDS traffic/block-iter 80KB -> 48KB; A rides L1/L2 in parallel.
//   - Math identical to R8 (passed, absmax 0.015625) -> absmax must not move.
// ===========================================================================

typedef __attribute__((ext_vector_type(8))) short    bf16x8;   // MFMA A/B frag
typedef __attribute__((ext_vector_type(4))) float    f32x4;    // MFMA C/D frag

__device__ __forceinline__ unsigned short f2bf(float x) {
    unsigned u = __float_as_uint(x);
    u += 0x7FFFu + ((u >> 16) & 1u);    // round-to-nearest-even
    return (unsigned short)(u >> 16);
}
__device__ __forceinline__ float bf2f(unsigned short h) {
    return __uint_as_float(((unsigned)h) << 16);
}
__device__ __forceinline__ void split2(float x, unsigned short& h, unsigned short& l) {
    h = f2bf(x);
    l = f2bf(x - bf2f(h));
}

// Frag-major (swizzled) offset for an A-operand matrix [M][K], kpan = K/32.
// Panel (m>>4, k>>5) is 512 elems; within: lane L=(quad*16+lr) elem j ->
// L*8+j where quad=(k>>3)&3, lr=m&15, j=k&7.
__device__ __forceinline__ size_t swz(int m, int k, int kpan) {
    return ((size_t)((m >> 4) * kpan + (k >> 5))) * 512
         + (size_t)((((k >> 3) & 3) * 16 + (m & 15)) * 8 + (k & 7));
}

// Async global->LDS DMA, 16B per lane. LDS dest = wave-uniform base + lane*16.
__device__ __forceinline__ void gld16(const unsigned short* g, unsigned short* l) {
    __builtin_amdgcn_global_load_lds(
        (const __attribute__((address_space(1))) unsigned int*)g,
        (__attribute__((address_space(3))) unsigned int*)l,
        16, 0, 0);
}

// ---------------------------------------------------------------------------
// All-weights split -> SWIZZLED h/l (weights are GEMM-A operands, kpan=32).
// Flat over [Wq|Wk1|Wk2|Wv]. Grid 2560 x 1024 elems.
__global__ __launch_bounds__(256) void weights_split_k(
    const float* __restrict__ Wq, const float* __restrict__ Wk1,
    const float* __restrict__ Wk2, const float* __restrict__ Wv,
    unsigned short* __restrict__ Wqh, unsigned short* __restrict__ Wql,
    unsigned short* __restrict__ Wk1h, unsigned short* __restrict__ Wk1l,
    unsigned short* __restrict__ Wk2h, unsigned short* __restrict__ Wk2l,
    unsigned short* __restrict__ Wvh, unsigned short* __restrict__ Wvl)
{
    const int gi = blockIdx.x;
    const float* src; unsigned short *H, *L; int base;
    if (gi < 512)       { src = Wq;  H = Wqh;  L = Wql;  base = gi; }
    else if (gi < 1024) { src = Wk1; H = Wk1h; L = Wk1l; base = gi - 512; }
    else if (gi < 1536) { src = Wk2; H = Wk2h; L = Wk2l; base = gi - 1024; }
    else                { src = Wv;  H = Wvh;  L = Wvl;  base = gi - 1536; }
    const size_t i = (size_t)base * 1024 + threadIdx.x * 4;
    const int m = (int)(i >> 10);
    const int k = (int)(i & 1023);
    const float4 v = *(const float4*)(src + i);
    ushort4 h, l;
    split2(v.x, h.x, l.x); split2(v.y, h.y, l.y);
    split2(v.z, h.z, l.z); split2(v.w, h.w, l.w);
    const size_t o = swz(m, k, 32);      // k&7 in {0,4}: 4 elems contiguous
    *(ushort4*)(H + o) = h;
    *(ushort4*)(L + o) = l;
}

// ---------------------------------------------------------------------------
// Transpose + split for the 3 inputs in one launch (z selects which).
// Row-major output (B operands of convs).
__global__ __launch_bounds__(256) void transpose3_k(
    const float* __restrict__ x0, const float* __restrict__ x1,
    const float* __restrict__ x2,
    unsigned short* __restrict__ t0h, unsigned short* __restrict__ t0l,
    unsigned short* __restrict__ t1h, unsigned short* __restrict__ t1l,
    unsigned short* __restrict__ t2h, unsigned short* __restrict__ t2l)
{
    const float* X; unsigned short *Th, *Tl;
    if (blockIdx.z == 0)      { X = x0; Th = t0h; Tl = t0l; }
    else if (blockIdx.z == 1) { X = x1; Th = t1h; Tl = t1l; }
    else                      { X = x2; Th = t2h; Tl = t2l; }

    __shared__ float t[32 * 33];
    const int tid = threadIdx.x;
    const int c0 = blockIdx.y * 32;
    const int p0 = blockIdx.x * 32;

    const int cl = tid >> 3;
    const int p4 = (tid & 7) * 4;
    const float4 v = *(const float4*)(X + (size_t)(c0 + cl) * 4096 + p0 + p4);
    t[(p4 + 0) * 33 + cl] = v.x;
    t[(p4 + 1) * 33 + cl] = v.y;
    t[(p4 + 2) * 33 + cl] = v.z;
    t[(p4 + 3) * 33 + cl] = v.w;
    __syncthreads();

    const int pl = tid >> 3;
    const int c4 = (tid & 7) * 4;
    ushort4 h, l;
    split2(t[pl * 33 + c4 + 0], h.x, l.x);
    split2(t[pl * 33 + c4 + 1], h.y, l.y);
    split2(t[pl * 33 + c4 + 2], h.z, l.z);
    split2(t[pl * 33 + c4 + 3], h.w, l.w);
    const size_t o = (size_t)(p0 + pl) * 1024 + c0 + c4;
    *(ushort4*)(Th + o) = h;
    *(ushort4*)(Tl + o) = l;
}

// Single-matrix transpose+split, row-major output (VT = B of final GEMM).
__global__ __launch_bounds__(256) void transpose1_k(
    const float* __restrict__ X,
    unsigned short* __restrict__ Th, unsigned short* __restrict__ Tl)
{
    __shared__ float t[32 * 33];
    const int tid = threadIdx.x;
    const int c0 = blockIdx.y * 32;
    const int p0 = blockIdx.x * 32;

    const int cl = tid >> 3;
    const int p4 = (tid & 7) * 4;
    const float4 v = *(const float4*)(X + (size_t)(c0 + cl) * 4096 + p0 + p4);
    t[(p4 + 0) * 33 + cl] = v.x;
    t[(p4 + 1) * 33 + cl] = v.y;
    t[(p4 + 2) * 33 + cl] = v.z;
    t[(p4 + 3) * 33 + cl] = v.w;
    __syncthreads();

    const int pl = tid >> 3;
    const int c4 = (tid & 7) * 4;
    ushort4 h, l;
    split2(t[pl * 33 + c4 + 0], h.x, l.x);
    split2(t[pl * 33 + c4 + 1], h.y, l.y);
    split2(t[pl * 33 + c4 + 2], h.z, l.z);
    split2(t[pl * 33 + c4 + 3], h.w, l.w);
    const size_t o = (size_t)(p0 + pl) * 1024 + c0 + c4;
    *(ushort4*)(Th + o) = h;
    *(ushort4*)(Tl + o) = l;
}

// ---------------------------------------------------------------------------
// GEMM core v4: A direct-from-global in SWIZZLED frag-major layout (coalesced
// 1KB per instr), B DMA-staged double-buffered in LDS (conflict-free).
// acc += A[m0+..][kbeg..kend) (x) B[n0+..][..). 128x128 tile, BK=32,
// 4 waves 2x2, wave 64x64 = 4x4 MFMA(16x16x32) tiles.
// TERMS=3: ah*bh + ah*bl + al*bh.  TERMS=2: ah*bh + ah*bl.
template<int TERMS>
__device__ __forceinline__ void gemm_core(
    const unsigned short* __restrict__ Ah, const unsigned short* __restrict__ Al,
    const unsigned short* __restrict__ Bh, const unsigned short* __restrict__ Bl,
    int ldkB, int kpanA, int kbeg, int kend, int m0, int n0,
    unsigned short* Bs_h, unsigned short* Bs_l,   // each [2][128*32]
    f32x4 (&acc)[4][4])
{
    const int tid  = threadIdx.x;
    const int lane = tid & 63;
    const int wv   = tid >> 6;
    const int wm   = (wv >> 1) * 64;
    const int wn   = (wv & 1) * 64;
    const int lr   = lane & 15;
    const int quad = lane >> 4;

    // --- B staging: waves {0,1} -> Bs_h, waves {2,3} -> Bs_l; 4 insts/wave ---
    const unsigned short* gsrc = (wv < 2) ? Bh : Bl;
    unsigned short* ldst = (wv < 2) ? Bs_h : Bs_l;
    const int tt0  = (wv & 1) * 4;
    const int lrow = lane >> 2;
    const int gseg = ((lane & 3) - ((lane >> 3) & 3)) & 3;  // store-side swizzle
    const unsigned short* gp[4];
#pragma unroll
    for (int u = 0; u < 4; ++u)
        gp[u] = gsrc + (size_t)(n0 + (tt0 + u) * 16 + lrow) * ldkB + kbeg + gseg * 8;

    // --- A frag pointers: swizzled layout -> contiguous lane*16B loads ---
    const int pk0 = kbeg >> 5;
    const unsigned short* ap[4];
    const unsigned short* apl[4];
#pragma unroll
    for (int i = 0; i < 4; ++i) {
        const size_t off = ((size_t)(((m0 + wm) >> 4) + i) * kpanA + pk0) * 512
                         + (size_t)lane * 8;
        ap[i] = Ah + off;
        apl[i] = (TERMS == 3) ? (Al + off) : nullptr;
    }

    const int rdseg = (quad + (lr >> 1)) & 3;               // LDS read-side swizzle

    // prologue: DMA first B slab into buf 0
#pragma unroll
    for (int u = 0; u < 4; ++u) {
        gld16(gp[u], ldst + (tt0 + u) * 512);
        gp[u] += 32;
    }

    int buf = 0;
    for (int k0 = kbeg; k0 < kend; k0 += 32) {
        __syncthreads();    // drains DMA issued last iter (a full compute phase old)

        // A frags: coalesced global loads, issued BEFORE next DMA so MFMA's
        // waitcnt retires them without draining the in-flight prefetch.
        bf16x8 afh[4], afl[4];
#pragma unroll
        for (int i = 0; i < 4; ++i) {
            afh[i] = *(const bf16x8*)ap[i];  ap[i] += 512;
            if (TERMS == 3) { afl[i] = *(const bf16x8*)apl[i]; apl[i] += 512; }
        }
        // prefetch next B slab -> other buffer
        if (k0 + 32 < kend) {
#pragma unroll
            for (int u = 0; u < 4; ++u) {
                gld16(gp[u], ldst + (buf ^ 1) * 4096 + (tt0 + u) * 512);
                gp[u] += 32;
            }
        }
        // B frags from current buffer
        bf16x8 bfh[4], bfl[4];
#pragma unroll
        for (int j = 0; j < 4; ++j) {
            const int rb = buf * 4096 + (wn + j * 16 + lr) * 32 + rdseg * 8;
            bfh[j] = *(const bf16x8*)(Bs_h + rb);
            bfl[j] = *(const bf16x8*)(Bs_l + rb);
        }
#pragma unroll
        for (int i = 0; i < 4; ++i)
#pragma unroll
            for (int j = 0; j < 4; ++j) {
                acc[i][j] = __builtin_amdgcn_mfma_f32_16x16x32_bf16(afh[i], bfh[j], acc[i][j], 0, 0, 0);
                acc[i][j] = __builtin_amdgcn_mfma_f32_16x16x32_bf16(afh[i], bfl[j], acc[i][j], 0, 0, 0);
                if (TERMS == 3)
                    acc[i][j] = __builtin_amdgcn_mfma_f32_16x16x32_bf16(afl[i], bfh[j], acc[i][j], 0, 0, 0);
            }
        buf ^= 1;
    }
}

#define GEMM_PROLOGUE()                                                 \
    __shared__ __align__(16) unsigned short Bs_h[2 * 128 * 32];         \
    __shared__ __align__(16) unsigned short Bs_l[2 * 128 * 32];         \
    f32x4 acc[4][4];                                                    \
    _Pragma("unroll") for (int i = 0; i < 4; ++i)                       \
    _Pragma("unroll") for (int j = 0; j < 4; ++j)                       \
    _Pragma("unroll") for (int r = 0; r < 4; ++r) acc[i][j][r] = 0.f;   \
    const int lane = threadIdx.x & 63;                                  \
    const int wv   = threadIdx.x >> 6;                                  \
    const int wm   = (wv >> 1) * 64;                                    \
    const int wn   = (wv & 1) * 64;                                     \
    const int lr   = lane & 15;                                         \
    const int quad = lane >> 4;                                         \
    (void)lane; (void)wv;

// ---------------------------------------------------------------------------
// ALL FOUR convs, one launch. m-tiles (blockIdx.y, 0..19) partition
// [Wq(4) | Wk1(4) | Wk2(4) | Wv(8)]. Grid (32,20) = 640 blocks. 3-term.
// Outputs: Q row-major h/l (B of logits); Kf/Kl SWIZZLED h/l (A of logits,
// viewed as [1024][2048]: m2=(ch<<1)|(px>>11), k2=px&2047, kpan=64);
// V f32 row-major (+bias), transposed later.
__global__ __launch_bounds__(256) void conv_all_k(
    const unsigned short* __restrict__ Wqh, const unsigned short* __restrict__ Wql,
    const unsigned short* __restrict__ Wk1h, const unsigned short* __restrict__ Wk1l,
    const unsigned short* __restrict__ Wk2h, const unsigned short* __restrict__ Wk2l,
    const unsigned short* __restrict__ Wvh, const unsigned short* __restrict__ Wvl,
    const unsigned short* __restrict__ xmTh, const unsigned short* __restrict__ xmTl,
    const unsigned short* __restrict__ xfTh, const unsigned short* __restrict__ xfTl,
    const unsigned short* __restrict__ xlTh, const unsigned short* __restrict__ xlTl,
    const float* __restrict__ bq, const float* __restrict__ bk1,
    const float* __restrict__ bk2, const float* __restrict__ bv,
    unsigned short* __restrict__ Qh, unsigned short* __restrict__ Ql,
    unsigned short* __restrict__ Kfh, unsigned short* __restrict__ Kfl,
    unsigned short* __restrict__ Klh, unsigned short* __restrict__ Kll,
    float* __restrict__ V)
{
    GEMM_PROLOGUE();
    const int mt = blockIdx.y;
    const unsigned short *Ah, *Al, *Bh, *Bl;
    const float* bias;
    unsigned short *Ch = nullptr, *Cl = nullptr;
    float* Cv = nullptr;
    int mloc, mode;
    if (mt < 4) {
        Ah = Wqh;  Al = Wql;  Bh = xmTh; Bl = xmTl; bias = bq;
        Ch = Qh;   Cl = Ql;   mloc = mt * 128;        mode = 0;
    } else if (mt < 8) {
        Ah = Wk1h; Al = Wk1l; Bh = xfTh; Bl = xfTl; bias = bk1;
        Ch = Kfh;  Cl = Kfl;  mloc = (mt - 4) * 128;  mode = 1;
    } else if (mt < 12) {
        Ah = Wk2h; Al = Wk2l; Bh = xlTh; Bl = xlTl; bias = bk2;
        Ch = Klh;  Cl = Kll;  mloc = (mt - 8) * 128;  mode = 1;
    } else {
        Ah = Wvh;  Al = Wvl;  Bh = xmTh; Bl = xmTl; bias = bv;
        Cv = V;    mloc = (mt - 12) * 128;            mode = 2;
    }
    const int n0 = blockIdx.x * 128;

    gemm_core<3>(Ah, Al, Bh, Bl, 1024, 32, 0, 1024, mloc, n0, Bs_h, Bs_l, acc);

#pragma unroll
    for (int i = 0; i < 4; ++i) {
        const int mb = mloc + wm + i * 16 + quad * 4;
#pragma unroll
        for (int j = 0; j < 4; ++j) {
            const int nn = n0 + wn + j * 16 + lr;
#pragma unroll
            for (int r = 0; r < 4; ++r) {
                const float v = acc[i][j][r] + bias[mb + r];
                if (mode == 2) {
                    Cv[(size_t)(mb + r) * 4096 + nn] = v;
                } else if (mode == 0) {
                    unsigned short h, l;
                    split2(v, h, l);
                    const size_t idx = (size_t)(mb + r) * 4096 + nn;
                    Ch[idx] = h;
                    Cl[idx] = l;
                } else {
                    // swizzled store for logits-A view [1024][2048]
                    const int m2 = ((mb + r) << 1) | (nn >> 11);
                    const int k2 = nn & 2047;
                    const size_t o = swz(m2, k2, 64);
                    unsigned short h, l;
                    split2(v, h, l);
                    Ch[o] = h;
                    Cl[o] = l;
                }
            }
        }
    }
}

// ---------------------------------------------------------------------------
// Fused logits, split-K: z = which(f/l)*4 + kslice(0..3), K=512 per block.
// A = Kf/Kl swizzled (kpan=64), B = Q row-major ldk=2048. Grid (8,8,8). 3-term.
__global__ __launch_bounds__(256) void logits_fused_k(
    const unsigned short* __restrict__ Kfh, const unsigned short* __restrict__ Kfl,
    const unsigned short* __restrict__ Klh, const unsigned short* __restrict__ Kll,
    const unsigned short* __restrict__ Qh, const unsigned short* __restrict__ Ql,
    float* __restrict__ Sfp, float* __restrict__ Slp)
{
    GEMM_PROLOGUE();
    const int which = blockIdx.z >> 2;
    const int slice = blockIdx.z & 3;
    const unsigned short* Ah = which ? Klh : Kfh;
    const unsigned short* Al = which ? Kll : Kfl;
    float* out = (which ? Slp : Sfp) + (size_t)slice * 1024 * 1024;
    const int m0 = blockIdx.y * 128;
    const int n0 = blockIdx.x * 128;

    gemm_core<3>(Ah, Al, Qh, Ql, 2048, 64, slice * 512, slice * 512 + 512, m0, n0,
                 Bs_h, Bs_l, acc);

#pragma unroll
    for (int i = 0; i < 4; ++i) {
        const int mb = m0 + wm + i * 16 + quad * 4;
#pragma unroll
        for (int j = 0; j < 4; ++j) {
            const int nn = n0 + wn + j * 16 + lr;
#pragma unroll
            for (int r = 0; r < 4; ++r)
                out[(size_t)(mb + r) * 1024 + nn] = acc[i][j][r];
        }
    }
}

// ---------------------------------------------------------------------------
// Final: out = gamma*(A (x) VT) + 0.5*(xf+xl). A = Am swizzled (kpan=32),
// B = VT row-major ldk=1024. Grid (32,8) = 256 blocks. 2-term.
__global__ __launch_bounds__(256) void gemm_final_k(
    const unsigned short* __restrict__ Amh,
    const unsigned short* __restrict__ VTh, const unsigned short* __restrict__ VTl,
    float* __restrict__ out,
    const float* __restrict__ xf, const float* __restrict__ xl,
    const float* __restrict__ gamma)
{
    GEMM_PROLOGUE();
    const int m0 = blockIdx.y * 128;
    const int n0 = blockIdx.x * 128;

    gemm_core<2>(Amh, nullptr, VTh, VTl, 1024, 32, 0, 1024, m0, n0, Bs_h, Bs_l, acc);

    const float g = gamma[0];
#pragma unroll
    for (int i = 0; i < 4; ++i) {
        const int mb = m0 + wm + i * 16 + quad * 4;
#pragma unroll
        for (int j = 0; j < 4; ++j) {
            const int nn = n0 + wn + j * 16 + lr;
#pragma unroll
            for (int r = 0; r < 4; ++r) {
                const size_t idx = (size_t)(mb + r) * 4096 + nn;
                out[idx] = g * acc[i][j][r] + 0.5f * (xf[idx] + xl[idx]);
            }
        }
    }
}

// ---------------------------------------------------------------------------
// Row softmax over 4-slice partial sums: A = sm(sum Sfp) + sm(sum Slp),
// bf16 hi only (final GEMM is 2-term), stored SWIZZLED (kpan=32).
__global__ __launch_bounds__(256) void softmax_add4_k(
    const float* __restrict__ Sfp, const float* __restrict__ Slp,
    unsigned short* __restrict__ Ah)
{
    const int row = blockIdx.x;
    const int tid = threadIdx.x;
    __shared__ float red[8];
    const size_t base = (size_t)row * 1024 + tid * 4;
    const size_t SL = (size_t)1024 * 1024;

    float4 vf = *(const float4*)(Sfp + base);
    float4 vl = *(const float4*)(Slp + base);
#pragma unroll
    for (int s = 1; s < 4; ++s) {
        const float4 a = *(const float4*)(Sfp + s * SL + base);
        const float4 b = *(const float4*)(Slp + s * SL + base);
        vf.x += a.x; vf.y += a.y; vf.z += a.z; vf.w += a.w;
        vl.x += b.x; vl.y += b.y; vl.z += b.z; vl.w += b.w;
    }

    float mf = fmaxf(fmaxf(vf.x, vf.y), fmaxf(vf.z, vf.w));
    float ml = fmaxf(fmaxf(vl.x, vl.y), fmaxf(vl.z, vl.w));
#pragma unroll
    for (int off = 32; off; off >>= 1) {
        mf = fmaxf(mf, __shfl_down(mf, off, 64));
        ml = fmaxf(ml, __shfl_down(ml, off, 64));
    }
    const int wave = tid >> 6;
    if ((tid & 63) == 0) { red[wave] = mf; red[4 + wave] = ml; }
    __syncthreads();
    mf = fmaxf(fmaxf(red[0], red[1]), fmaxf(red[2], red[3]));
    ml = fmaxf(fmaxf(red[4], red[5]), fmaxf(red[6], red[7]));
    __syncthreads();

    const float4 ef = make_float4(expf(vf.x - mf), expf(vf.y - mf),
                                  expf(vf.z - mf), expf(vf.w - mf));
    const float4 el = make_float4(expf(vl.x - ml), expf(vl.y - ml),
                                  expf(vl.z - ml), expf(vl.w - ml));
    float sf = ef.x + ef.y + ef.z + ef.w;
    float sl = el.x + el.y + el.z + el.w;
#pragma unroll
    for (int off = 32; off; off >>= 1) {
        sf += __shfl_down(sf, off, 64);
        sl += __shfl_down(sl, off, 64);
    }
    if ((tid & 63) == 0) { red[wave] = sf; red[4 + wave] = sl; }
    __syncthreads();
    sf = red[0] + red[1] + red[2] + red[3];
    sl = red[4] + red[5] + red[6] + red[7];

    const float rf = 1.f / sf, rl = 1.f / sl;
    ushort4 h;
    h.x = f2bf(ef.x * rf + el.x * rl);
    h.y = f2bf(ef.y * rf + el.y * rl);
    h.z = f2bf(ef.z * rf + el.z * rl);
    h.w = f2bf(ef.w * rf + el.w * rl);
    const size_t o = swz(row, tid * 4, 32);   // 4 elems contiguous ((4t)&7 in {0,4})
    *(ushort4*)(Ah + o) = h;
}

__global__ void noop_k(float* p) { if (threadIdx.x == 1024) p[0] = 0.f; }

// ===========================================================================
extern "C" void kernel_launch(void* const* d_in, const int* in_sizes, int n_in,
                              void* d_out, int out_size, void* d_ws, size_t ws_size,
                              hipStream_t stream) {
    (void)in_sizes; (void)n_in; (void)out_size;
    const float* xf  = (const float*)d_in[0];
    const float* xm  = (const float*)d_in[1];
    const float* xl  = (const float*)d_in[2];
    const float* Wq  = (const float*)d_in[3];
    const float* bq  = (const float*)d_in[4];
    const float* Wk1 = (const float*)d_in[5];
    const float* bk1 = (const float*)d_in[6];
    const float* Wk2 = (const float*)d_in[7];
    const float* bk2 = (const float*)d_in[8];
    const float* Wv  = (const float*)d_in[9];
    const float* bv  = (const float*)d_in[10];
    const float* gamma = (const float*)d_in[11];
    float* out = (float*)d_out;

    const size_t MB = 1024 * 1024;
    if (ws_size < 98 * MB) {
        noop_k<<<dim3(1), dim3(64), 0, stream>>>((float*)d_ws);
        return;
    }

    // ---- workspace layout (byte offsets, 98 MB total) ----
    char* p = (char*)d_ws;
    unsigned short* xmT_h = (unsigned short*)(p + 0 * MB);    // [4096][1024] bf16, row-major
    unsigned short* xmT_l = (unsigned short*)(p + 8 * MB);
    unsigned short* xfT_h = (unsigned short*)(p + 16 * MB);
    unsigned short* xfT_l = (unsigned short*)(p + 24 * MB);
    unsigned short* xlT_h = (unsigned short*)(p + 32 * MB);
    unsigned short* xlT_l = (unsigned short*)(p + 40 * MB);
    unsigned short* Wq_h  = (unsigned short*)(p + 48 * MB);   // swizzled
    unsigned short* Wq_l  = (unsigned short*)(p + 49 * MB);
    unsigned short* Wk1_h = (unsigned short*)(p + 50 * MB);
    unsigned short* Wk1_l = (unsigned short*)(p + 51 * MB);
    unsigned short* Wk2_h = (unsigned short*)(p + 52 * MB);
    unsigned short* Wk2_l = (unsigned short*)(p + 53 * MB);
    unsigned short* Wv_h  = (unsigned short*)(p + 54 * MB);
    unsigned short* Wv_l  = (unsigned short*)(p + 56 * MB);
    unsigned short* Q_h   = (unsigned short*)(p + 58 * MB);   // row-major [1024][2048]
    unsigned short* Q_l   = (unsigned short*)(p + 62 * MB);
    unsigned short* Kf_h  = (unsigned short*)(p + 66 * MB);   // swizzled [1024][2048]
    unsigned short* Kf_l  = (unsigned short*)(p + 70 * MB);
    unsigned short* Kl_h  = (unsigned short*)(p + 74 * MB);
    unsigned short* Kl_l  = (unsigned short*)(p + 78 * MB);
    float*          V     = (float*)(p + 82 * MB);            // [1024][4096] f32 (+bias)
    // lifetime-based reuse (launch order: convs -> logits -> V transpose ->
    // softmax -> final):
    float*          Sfp  = (float*)(p + 16 * MB);  // [4][1024][1024] over xfT (dead after convs)
    float*          Slp  = (float*)(p + 32 * MB);  // over xlT
    unsigned short* VT_h = xmT_h;                  // over xmT (dead after convs)
    unsigned short* VT_l = xmT_l;
    unsigned short* Am_h = (unsigned short*)(p + 74 * MB);  // swizzled, over Kl (dead after logits)

    const dim3 blk(256);
    // prep (2 launches): transpose+split the 3 inputs; split the 4 weights
    transpose3_k<<<dim3(128, 32, 3), blk, 0, stream>>>(
        xm, xf, xl, xmT_h, xmT_l, xfT_h, xfT_l, xlT_h, xlT_l);
    weights_split_k<<<dim3(2560), blk, 0, stream>>>(
        Wq, Wk1, Wk2, Wv, Wq_h, Wq_l, Wk1_h, Wk1_l, Wk2_h, Wk2_l, Wv_h, Wv_l);
    // ALL convs, one launch (640 blocks)
    conv_all_k<<<dim3(32, 20), blk, 0, stream>>>(
        Wq_h, Wq_l, Wk1_h, Wk1_l, Wk2_h, Wk2_l, Wv_h, Wv_l,
        xmT_h, xmT_l, xfT_h, xfT_l, xlT_h, xlT_l,
        bq, bk1, bk2, bv,
        Q_h, Q_l, Kf_h, Kf_l, Kl_h, Kl_l, V);
    // logits fused + split-K=4 (512 blocks) -> partials over xfT/xlT regions
    logits_fused_k<<<dim3(8, 8, 8), blk, 0, stream>>>(
        Kf_h, Kf_l, Kl_h, Kl_l, Q_h, Q_l, Sfp, Slp);
    // VT = transpose+split(V) over dead xmT region
    transpose1_k<<<dim3(128, 32), blk, 0, stream>>>(V, VT_h, VT_l);
    // A = softmax(sum Sfp) + softmax(sum Slp), swizzled bf16-hi over dead Kl
    softmax_add4_k<<<dim3(1024), blk, 0, stream>>>(Sfp, Slp, Am_h);
    // out = gamma*(A (x) VT) + (xf+xl)/2   (256 blocks)
    gemm_final_k<<<dim3(32, 8), blk, 0, stream>>>(
        Am_h, VT_h, VT_l, out, xf, xl, gamma);
}